// Round 2
// baseline (2037.913 us; speedup 1.0000x reference)
//
#include <hip/hip_runtime.h>
#include <hip/hip_bf16.h>

#define NN 50000
#define EE 800000
#define HD 64
#define LL 14
#define IND 128
#define OUTD 112

// ---------------- CSR build ----------------

__global__ void k_hist(const int* __restrict__ ei, int* __restrict__ deg) {
    int e = blockIdx.x * blockDim.x + threadIdx.x;
    if (e < EE) atomicAdd(&deg[ei[EE + e]], 1);
}

__global__ __launch_bounds__(1024) void k_scan1(const int* __restrict__ deg,
                                                int* __restrict__ excl,
                                                int* __restrict__ bsum) {
    __shared__ int ws[16];
    int tid = threadIdx.x, lane = tid & 63, w = tid >> 6;
    int gid = blockIdx.x * 1024 + tid;
    int v = (gid < NN) ? deg[gid] : 0;
    int x = v;
    #pragma unroll
    for (int d = 1; d < 64; d <<= 1) {
        int y = __shfl_up(x, d);
        if (lane >= d) x += y;
    }
    if (lane == 63) ws[w] = x;
    __syncthreads();
    if (tid == 0) {
        int acc = 0;
        for (int i = 0; i < 16; i++) { int t = ws[i]; ws[i] = acc; acc += t; }
        bsum[blockIdx.x] = acc;
    }
    __syncthreads();
    if (gid < NN) excl[gid] = x - v + ws[w];
}

__global__ void k_scan2(const int* __restrict__ bsum, int* __restrict__ boff, int nb) {
    if (threadIdx.x == 0) {
        int acc = 0;
        for (int i = 0; i < nb; i++) { boff[i] = acc; acc += bsum[i]; }
    }
}

__global__ __launch_bounds__(1024) void k_scan3(int* __restrict__ rp, int* __restrict__ cur,
                                                const int* __restrict__ boff) {
    int gid = blockIdx.x * 1024 + threadIdx.x;
    if (gid < NN) {
        int v = rp[gid] + boff[blockIdx.x];
        rp[gid] = v;
        cur[gid] = v;
    }
    if (gid == 0) rp[NN] = EE;
}

__global__ void k_scatter(const int* __restrict__ ei, int* __restrict__ cur,
                          int* __restrict__ csrc) {
    int e = blockIdx.x * blockDim.x + threadIdx.x;
    if (e < EE) {
        int d = ei[EE + e];
        int pos = atomicAdd(&cur[d], 1);
        csrc[pos] = ei[e];
    }
}

// ---------------- Encoder: h = x @ enc_W + enc_b ----------------

__global__ __launch_bounds__(256) void k_enc(const float* __restrict__ x,
                                             const float* __restrict__ W,
                                             const float* __restrict__ b,
                                             float* __restrict__ h) {
    __shared__ float Ws[IND * HD];  // 32 KB
    int tid = threadIdx.x;
    for (int i = tid; i < IND * HD; i += 256) Ws[i] = W[i];
    __syncthreads();
    int lane = tid & 63, w = tid >> 6;
    int node = blockIdx.x * 4 + w;
    float x0 = x[node * IND + lane];
    float x1 = x[node * IND + 64 + lane];
    float acc = b[lane];
    #pragma unroll
    for (int k = 0; k < 64; k++) acc += __shfl(x0, k) * Ws[k * HD + lane];
    #pragma unroll
    for (int k = 0; k < 64; k++) acc += __shfl(x1, k) * Ws[(64 + k) * HD + lane];
    h[node * HD + lane] = acc;
}

// ---------------- Pre-norm: h2 = relu(LN(h)) ----------------

__global__ __launch_bounds__(256) void k_prenorm(const float* __restrict__ h,
                                                 float* __restrict__ h2,
                                                 const float* __restrict__ g,
                                                 const float* __restrict__ b) {
    int tid = threadIdx.x, lane = tid & 63, w = tid >> 6;
    int node = blockIdx.x * 4 + w;
    float v = h[node * HD + lane];
    float s = v;
    #pragma unroll
    for (int d = 32; d; d >>= 1) s += __shfl_xor(s, d);
    float mu = s * (1.f / 64.f);
    float dd = v - mu;
    float q = dd * dd;
    #pragma unroll
    for (int d = 32; d; d >>= 1) q += __shfl_xor(q, d);
    float inv = rsqrtf(q * (1.f / 64.f) + 1e-5f);
    float y = dd * inv * g[lane] + b[lane];
    h2[node * HD + lane] = fmaxf(y, 0.f);
}

// ---------------- GENConv layer (online softmax aggregation + matmul) ----------------

__global__ __launch_bounds__(256) void k_layer(const float* __restrict__ h2,
                                               const float* __restrict__ hres,
                                               float* __restrict__ hout,
                                               const int* __restrict__ rp,
                                               const int* __restrict__ csrc,
                                               const float* __restrict__ W,
                                               const float* __restrict__ b) {
    __shared__ float Ws[HD * HD];  // 16 KB
    int tid = threadIdx.x;
    for (int i = tid; i < HD * HD; i += 256) Ws[i] = W[i];
    __syncthreads();
    int lane = tid & 63, w = tid >> 6;
    int node = blockIdx.x * 4 + w;
    int beg = rp[node], end = rp[node + 1];
    float m = -INFINITY, s = 0.f, n = 0.f;
    for (int e = beg; e < end; ++e) {
        int src = csrc[e];
        float v = h2[src * HD + lane];
        float msg = fmaxf(v, 0.f) + 1e-7f;
        float nm = fmaxf(m, msg);
        float sc = __expf(m - nm);   // exp(-inf)=0 handles first edge
        float p = __expf(msg - nm);
        s = s * sc + p;
        n = n * sc + p * msg;
        m = nm;
    }
    float agg = n / fmaxf(s, 1e-16f);  // 0 for isolated nodes (s==0 -> n==0)
    float xv = h2[node * HD + lane] + agg;
    float acc = b[lane];
    #pragma unroll
    for (int k = 0; k < 64; k++) acc += __shfl(xv, k) * Ws[k * HD + lane];
    if (hres) acc += hres[node * HD + lane];
    hout[node * HD + lane] = acc;
}

// ---------------- Predictor: out = h @ pred_W + pred_b ----------------

__global__ __launch_bounds__(256) void k_pred(const float* __restrict__ h,
                                              const float* __restrict__ W,
                                              const float* __restrict__ b,
                                              float* __restrict__ out) {
    __shared__ float Ws[HD * OUTD];  // 28 KB
    int tid = threadIdx.x;
    for (int i = tid; i < HD * OUTD; i += 256) Ws[i] = W[i];
    __syncthreads();
    int lane = tid & 63, w = tid >> 6;
    int node = blockIdx.x * 4 + w;
    float x = h[node * HD + lane];
    float a0 = b[lane];
    float a1 = (lane < OUTD - 64) ? b[64 + lane] : 0.f;
    #pragma unroll
    for (int k = 0; k < 64; k++) {
        float xk = __shfl(x, k);
        a0 += xk * Ws[k * OUTD + lane];
        if (lane < OUTD - 64) a1 += xk * Ws[k * OUTD + 64 + lane];
    }
    out[node * OUTD + lane] = a0;
    if (lane < OUTD - 64) out[node * OUTD + 64 + lane] = a1;
}

// ---------------- Launch ----------------

extern "C" void kernel_launch(void* const* d_in, const int* in_sizes, int n_in,
                              void* d_out, int out_size, void* d_ws, size_t ws_size,
                              hipStream_t stream) {
    const float* x    = (const float*)d_in[0];
    const int*   ei   = (const int*)d_in[1];
    const float* encW = (const float*)d_in[2];
    const float* encb = (const float*)d_in[3];
    const float* lng  = (const float*)d_in[4];
    const float* lnb  = (const float*)d_in[5];
    const float* mlpW = (const float*)d_in[6];
    const float* mlpb = (const float*)d_in[7];
    const float* pW   = (const float*)d_in[8];
    const float* pb   = (const float*)d_in[9];
    float* out = (float*)d_out;

    float* hA = (float*)d_ws;
    float* hB = hA + (size_t)NN * HD;
    float* h2 = hB + (size_t)NN * HD;
    int* rp   = (int*)(h2 + (size_t)NN * HD);
    int* cur  = rp + (NN + 1);
    int* csrc = cur + NN;
    int* bsum = csrc + EE;
    int* boff = bsum + 64;

    // CSR build (per call; ws is re-poisoned each launch)
    hipMemsetAsync(cur, 0, NN * sizeof(int), stream);
    k_hist<<<(EE + 255) / 256, 256, 0, stream>>>(ei, cur);
    const int NB = (NN + 1023) / 1024;  // 49
    k_scan1<<<NB, 1024, 0, stream>>>(cur, rp, bsum);
    k_scan2<<<1, 64, 0, stream>>>(bsum, boff, NB);
    k_scan3<<<NB, 1024, 0, stream>>>(rp, cur, boff);
    k_scatter<<<(EE + 255) / 256, 256, 0, stream>>>(ei, cur, csrc);

    // Encoder
    k_enc<<<NN / 4, 256, 0, stream>>>(x, encW, encb, hA);

    // 14 GENConv layers
    float* hc = hA;
    float* hn = hB;
    for (int l = 0; l < LL; ++l) {
        const float* gin;
        const float* res;
        if (l == 0) {
            gin = hc; res = nullptr;
        } else {
            k_prenorm<<<NN / 4, 256, 0, stream>>>(hc, h2, lng + (size_t)(l - 1) * HD,
                                                  lnb + (size_t)(l - 1) * HD);
            gin = h2; res = hc;
        }
        k_layer<<<NN / 4, 256, 0, stream>>>(gin, res, hn, rp, csrc,
                                            mlpW + (size_t)l * HD * HD,
                                            mlpb + (size_t)l * HD);
        float* t = hc; hc = hn; hn = t;
    }

    // Predictor
    k_pred<<<NN / 4, 256, 0, stream>>>(hc, pW, pb, out);
}

// Round 3
// 1186.277 us; speedup vs baseline: 1.7179x; 1.7179x over previous
//
#include <hip/hip_runtime.h>
#include <hip/hip_bf16.h>

#define NN 50000
#define EE 800000
#define HD 64
#define LL 14
#define IND 128
#define OUTD 112

__device__ __forceinline__ float rl(float v, int k) {
    return __int_as_float(__builtin_amdgcn_readlane(__float_as_int(v), k));
}

// ---------------- CSR build ----------------

__global__ void k_hist(const int* __restrict__ ei, int* __restrict__ deg) {
    int e = blockIdx.x * blockDim.x + threadIdx.x;
    if (e < EE) atomicAdd(&deg[ei[EE + e]], 1);
}

__global__ __launch_bounds__(1024) void k_scan1(const int* __restrict__ deg,
                                                int* __restrict__ excl,
                                                int* __restrict__ bsum) {
    __shared__ int ws[16];
    int tid = threadIdx.x, lane = tid & 63, w = tid >> 6;
    int gid = blockIdx.x * 1024 + tid;
    int v = (gid < NN) ? deg[gid] : 0;
    int x = v;
    #pragma unroll
    for (int d = 1; d < 64; d <<= 1) {
        int y = __shfl_up(x, d);
        if (lane >= d) x += y;
    }
    if (lane == 63) ws[w] = x;
    __syncthreads();
    if (tid == 0) {
        int acc = 0;
        for (int i = 0; i < 16; i++) { int t = ws[i]; ws[i] = acc; acc += t; }
        bsum[blockIdx.x] = acc;
    }
    __syncthreads();
    if (gid < NN) excl[gid] = x - v + ws[w];
}

__global__ void k_scan2(const int* __restrict__ bsum, int* __restrict__ boff, int nb) {
    if (threadIdx.x == 0) {
        int acc = 0;
        for (int i = 0; i < nb; i++) { boff[i] = acc; acc += bsum[i]; }
    }
}

__global__ __launch_bounds__(1024) void k_scan3(int* __restrict__ rp, int* __restrict__ cur,
                                                const int* __restrict__ boff) {
    int gid = blockIdx.x * 1024 + threadIdx.x;
    if (gid < NN) {
        int v = rp[gid] + boff[blockIdx.x];
        rp[gid] = v;
        cur[gid] = v;
    }
    if (gid == 0) rp[NN] = EE;
}

__global__ void k_scatter(const int* __restrict__ ei, int* __restrict__ cur,
                          int* __restrict__ csrc) {
    int e = blockIdx.x * blockDim.x + threadIdx.x;
    if (e < EE) {
        int d = ei[EE + e];
        int pos = atomicAdd(&cur[d], 1);
        csrc[pos] = ei[e];
    }
}

// ---------------- Encoder: h = x @ enc_W + enc_b ----------------

__global__ __launch_bounds__(256) void k_enc(const float* __restrict__ x,
                                             const float* __restrict__ W,
                                             const float* __restrict__ b,
                                             float* __restrict__ h) {
    __shared__ float Ws[IND * HD];  // 32 KB
    int tid = threadIdx.x;
    for (int i = tid; i < IND * HD; i += 256) Ws[i] = W[i];
    __syncthreads();
    int lane = tid & 63, w = tid >> 6;
    int node = blockIdx.x * 4 + w;
    float x0 = x[node * IND + lane];
    float x1 = x[node * IND + 64 + lane];
    float acc = b[lane];
    #pragma unroll
    for (int k = 0; k < 64; k++) acc += rl(x0, k) * Ws[k * HD + lane];
    #pragma unroll
    for (int k = 0; k < 64; k++) acc += rl(x1, k) * Ws[(64 + k) * HD + lane];
    h[node * HD + lane] = acc;
}

// ---------------- GENConv layer: online-softmax agg + matmul + residual
//                  + fused next-layer prenorm (relu(LayerNorm)) ----------------

__global__ __launch_bounds__(256) void k_layer(const float* __restrict__ h2in,
                                               const float* __restrict__ hres,
                                               float* __restrict__ hout,
                                               float* __restrict__ h2out,
                                               const int* __restrict__ rp,
                                               const int* __restrict__ csrc,
                                               const float* __restrict__ W,
                                               const float* __restrict__ b,
                                               const float* __restrict__ gnext,
                                               const float* __restrict__ bnext) {
    __shared__ float Ws[HD * HD];  // 16 KB
    int tid = threadIdx.x;
    for (int i = tid; i < HD * HD; i += 256) Ws[i] = W[i];
    __syncthreads();
    int lane = tid & 63, w = tid >> 6;
    int node = blockIdx.x * 4 + w;
    int beg = rp[node], end = rp[node + 1];

    float m = -INFINITY, s = 0.f, n = 0.f;
    int e = beg;
    // batch-4: 4 independent gathers in flight, parallel softmax batch update
    for (; e + 4 <= end; e += 4) {
        int i0 = csrc[e], i1 = csrc[e + 1], i2 = csrc[e + 2], i3 = csrc[e + 3];
        float v0 = h2in[i0 * HD + lane];
        float v1 = h2in[i1 * HD + lane];
        float v2 = h2in[i2 * HD + lane];
        float v3 = h2in[i3 * HD + lane];
        float m0 = fmaxf(v0, 0.f) + 1e-7f;
        float m1 = fmaxf(v1, 0.f) + 1e-7f;
        float m2 = fmaxf(v2, 0.f) + 1e-7f;
        float m3 = fmaxf(v3, 0.f) + 1e-7f;
        float nm = fmaxf(m, fmaxf(fmaxf(m0, m1), fmaxf(m2, m3)));
        float sc = __expf(m - nm);          // exp(-inf)=0 on first batch
        float p0 = __expf(m0 - nm);
        float p1 = __expf(m1 - nm);
        float p2 = __expf(m2 - nm);
        float p3 = __expf(m3 - nm);
        s = s * sc + ((p0 + p1) + (p2 + p3));
        n = n * sc + ((p0 * m0 + p1 * m1) + (p2 * m2 + p3 * m3));
        m = nm;
    }
    for (; e < end; ++e) {
        int i0 = csrc[e];
        float v = h2in[i0 * HD + lane];
        float msg = fmaxf(v, 0.f) + 1e-7f;
        float nm = fmaxf(m, msg);
        float sc = __expf(m - nm);
        float p = __expf(msg - nm);
        s = s * sc + p;
        n = n * sc + p * msg;
        m = nm;
    }
    float agg = n / fmaxf(s, 1e-16f);  // 0 for isolated nodes
    float xv = h2in[node * HD + lane] + agg;

    float acc = b[lane];
    #pragma unroll
    for (int k = 0; k < 64; k++) acc += rl(xv, k) * Ws[k * HD + lane];
    if (hres) acc += hres[node * HD + lane];
    hout[node * HD + lane] = acc;

    // fused prenorm for the next layer: h2out = relu(LN(acc))
    if (h2out) {
        float ssum = acc;
        #pragma unroll
        for (int d = 32; d; d >>= 1) ssum += __shfl_xor(ssum, d);
        float mu = ssum * (1.f / 64.f);
        float dd = acc - mu;
        float q = dd * dd;
        #pragma unroll
        for (int d = 32; d; d >>= 1) q += __shfl_xor(q, d);
        float inv = rsqrtf(q * (1.f / 64.f) + 1e-5f);
        float y = dd * inv * gnext[lane] + bnext[lane];
        h2out[node * HD + lane] = fmaxf(y, 0.f);
    }
}

// ---------------- Predictor: out = h @ pred_W + pred_b ----------------

__global__ __launch_bounds__(256) void k_pred(const float* __restrict__ h,
                                              const float* __restrict__ W,
                                              const float* __restrict__ b,
                                              float* __restrict__ out) {
    __shared__ float Ws[HD * OUTD];  // 28 KB
    int tid = threadIdx.x;
    for (int i = tid; i < HD * OUTD; i += 256) Ws[i] = W[i];
    __syncthreads();
    int lane = tid & 63, w = tid >> 6;
    int node = blockIdx.x * 4 + w;
    float x = h[node * HD + lane];
    float a0 = b[lane];
    float a1 = (lane < OUTD - 64) ? b[64 + lane] : 0.f;
    #pragma unroll
    for (int k = 0; k < 64; k++) {
        float xk = rl(x, k);
        a0 += xk * Ws[k * OUTD + lane];
        if (lane < OUTD - 64) a1 += xk * Ws[k * OUTD + 64 + lane];
    }
    out[node * OUTD + lane] = a0;
    if (lane < OUTD - 64) out[node * OUTD + 64 + lane] = a1;
}

// ---------------- Launch ----------------

extern "C" void kernel_launch(void* const* d_in, const int* in_sizes, int n_in,
                              void* d_out, int out_size, void* d_ws, size_t ws_size,
                              hipStream_t stream) {
    const float* x    = (const float*)d_in[0];
    const int*   ei   = (const int*)d_in[1];
    const float* encW = (const float*)d_in[2];
    const float* encb = (const float*)d_in[3];
    const float* lng  = (const float*)d_in[4];
    const float* lnb  = (const float*)d_in[5];
    const float* mlpW = (const float*)d_in[6];
    const float* mlpb = (const float*)d_in[7];
    const float* pW   = (const float*)d_in[8];
    const float* pb   = (const float*)d_in[9];
    float* out = (float*)d_out;

    float* hA  = (float*)d_ws;
    float* hB  = hA + (size_t)NN * HD;
    float* h2A = hB + (size_t)NN * HD;
    float* h2B = h2A + (size_t)NN * HD;
    int* rp   = (int*)(h2B + (size_t)NN * HD);
    int* cur  = rp + (NN + 1);
    int* csrc = cur + NN;
    int* bsum = csrc + EE;
    int* boff = bsum + 64;

    // CSR build (per call; ws is re-poisoned each launch)
    hipMemsetAsync(cur, 0, NN * sizeof(int), stream);
    k_hist<<<(EE + 255) / 256, 256, 0, stream>>>(ei, cur);
    const int NB = (NN + 1023) / 1024;  // 49
    k_scan1<<<NB, 1024, 0, stream>>>(cur, rp, bsum);
    k_scan2<<<1, 64, 0, stream>>>(bsum, boff, NB);
    k_scan3<<<NB, 1024, 0, stream>>>(rp, cur, boff);
    k_scatter<<<(EE + 255) / 256, 256, 0, stream>>>(ei, cur, csrc);

    // Encoder -> h_0 in hA
    k_enc<<<NN / 4, 256, 0, stream>>>(x, encW, encb, hA);

    // Layer 0: gin = h_0 (no prenorm, no residual); writes h_1 -> hB,
    // and fused prenorm(g[0],b[0]) -> h2A for layer 1.
    k_layer<<<NN / 4, 256, 0, stream>>>(hA, nullptr, hB, h2A, rp, csrc,
                                        mlpW, mlpb, lng, lnb);

    float* hres = hB;   // h_1
    float* hdst = hA;
    float* gcur = h2A;
    float* gnxt = h2B;
    for (int l = 1; l < LL; ++l) {
        bool last = (l == LL - 1);
        k_layer<<<NN / 4, 256, 0, stream>>>(gcur, hres, hdst,
                                            last ? nullptr : gnxt,
                                            rp, csrc,
                                            mlpW + (size_t)l * HD * HD,
                                            mlpb + (size_t)l * HD,
                                            last ? nullptr : lng + (size_t)l * HD,
                                            last ? nullptr : lnb + (size_t)l * HD);
        float* t = hres; hres = hdst; hdst = t;
        t = gcur; gcur = gnxt; gnxt = t;
    }

    // Predictor on h_14 (= hres after final swap)
    k_pred<<<NN / 4, 256, 0, stream>>>(hres, pW, pb, out);
}

// Round 4
// 938.824 us; speedup vs baseline: 2.1707x; 1.2636x over previous
//
#include <hip/hip_runtime.h>
#include <hip/hip_bf16.h>

#define NN 50000
#define EE 800000
#define HD 64
#define LL 14
#define IND 128
#define OUTD 112

__device__ __forceinline__ float rl(float v, int k) {
    return __int_as_float(__builtin_amdgcn_readlane(__float_as_int(v), k));
}

// ---------------- CSR build ----------------

__global__ void k_hist(const int* __restrict__ ei, int* __restrict__ deg) {
    int e = blockIdx.x * blockDim.x + threadIdx.x;
    if (e < EE) atomicAdd(&deg[ei[EE + e]], 1);
}

__global__ __launch_bounds__(1024) void k_scan1(const int* __restrict__ deg,
                                                int* __restrict__ excl,
                                                int* __restrict__ bsum) {
    __shared__ int ws[16];
    int tid = threadIdx.x, lane = tid & 63, w = tid >> 6;
    int gid = blockIdx.x * 1024 + tid;
    int v = (gid < NN) ? deg[gid] : 0;
    int x = v;
    #pragma unroll
    for (int d = 1; d < 64; d <<= 1) {
        int y = __shfl_up(x, d);
        if (lane >= d) x += y;
    }
    if (lane == 63) ws[w] = x;
    __syncthreads();
    if (tid == 0) {
        int acc = 0;
        for (int i = 0; i < 16; i++) { int t = ws[i]; ws[i] = acc; acc += t; }
        bsum[blockIdx.x] = acc;
    }
    __syncthreads();
    if (gid < NN) excl[gid] = x - v + ws[w];
}

__global__ void k_scan2(const int* __restrict__ bsum, int* __restrict__ boff, int nb) {
    if (threadIdx.x == 0) {
        int acc = 0;
        for (int i = 0; i < nb; i++) { boff[i] = acc; acc += bsum[i]; }
    }
}

__global__ __launch_bounds__(1024) void k_scan3(int* __restrict__ rp, int* __restrict__ cur,
                                                const int* __restrict__ boff) {
    int gid = blockIdx.x * 1024 + threadIdx.x;
    if (gid < NN) {
        int v = rp[gid] + boff[blockIdx.x];
        rp[gid] = v;
        cur[gid] = v;
    }
    if (gid == 0) rp[NN] = EE;
}

__global__ void k_scatter(const int* __restrict__ ei, int* __restrict__ cur,
                          int* __restrict__ csrc) {
    int e = blockIdx.x * blockDim.x + threadIdx.x;
    if (e < EE) {
        int d = ei[EE + e];
        int pos = atomicAdd(&cur[d], 1);
        csrc[pos] = ei[e];
    }
}

// ---------------- Encoder: h = x @ enc_W + enc_b ----------------

__global__ __launch_bounds__(256) void k_enc(const float* __restrict__ x,
                                             const float* __restrict__ W,
                                             const float* __restrict__ b,
                                             float* __restrict__ h) {
    __shared__ float Ws[IND * HD];  // 32 KB
    int tid = threadIdx.x;
    for (int i = tid; i < IND * HD; i += 256) Ws[i] = W[i];
    __syncthreads();
    int lane = tid & 63, w = tid >> 6;
    int node = blockIdx.x * 4 + w;
    float x0 = x[node * IND + lane];
    float x1 = x[node * IND + 64 + lane];
    float acc = b[lane];
    #pragma unroll
    for (int k = 0; k < 64; k++) acc += rl(x0, k) * Ws[k * HD + lane];
    #pragma unroll
    for (int k = 0; k < 64; k++) acc += rl(x1, k) * Ws[(64 + k) * HD + lane];
    h[node * HD + lane] = acc;
}

// ---------------- GENConv layer: softmax agg (scale-invariant, no running max)
//                  + matmul + residual + fused next-layer prenorm ----------------

__global__ __launch_bounds__(256) void k_layer(const float* __restrict__ h2in,
                                               const float* __restrict__ hres,
                                               float* __restrict__ hout,
                                               float* __restrict__ h2out,
                                               const int* __restrict__ rp,
                                               const int* __restrict__ csrc,
                                               const float* __restrict__ W,
                                               const float* __restrict__ b,
                                               const float* __restrict__ gnext,
                                               const float* __restrict__ bnext) {
    __shared__ float Ws[HD * HD];  // 16 KB
    int tid = threadIdx.x;
    #pragma unroll
    for (int i = 0; i < 16; i++) Ws[i * 256 + tid] = W[i * 256 + tid];
    __syncthreads();
    int lane = tid & 63, w = tid >> 6;
    int node = blockIdx.x * 4 + w;
    int beg = rp[node], end = rp[node + 1];
    int deg = end - beg;

    // msg = relu(v)+eps is bounded (LN output <= sqrt(63); clamp 50 as insurance),
    // so exp(msg) is overflow-safe and agg = sum(p*msg)/sum(p) needs no max shift.
    float s = 0.f, n = 0.f;
    for (int chunk = 0; chunk < deg; chunk += 64) {
        int cnt = min(64, deg - chunk);
        int myidx = 0;
        if (chunk + lane < deg) myidx = csrc[beg + chunk + lane];
        int k = 0;
        for (; k + 8 <= cnt; k += 8) {
            #pragma unroll
            for (int j = 0; j < 8; ++j) {
                int src = __builtin_amdgcn_readlane(myidx, k + j);
                float v = h2in[(size_t)src * HD + lane];
                float msg = fminf(fmaxf(v, 0.f) + 1e-7f, 50.f);
                float p = __expf(msg);
                s += p;
                n = fmaf(p, msg, n);
            }
        }
        for (; k < cnt; ++k) {
            int src = __builtin_amdgcn_readlane(myidx, k);
            float v = h2in[(size_t)src * HD + lane];
            float msg = fminf(fmaxf(v, 0.f) + 1e-7f, 50.f);
            float p = __expf(msg);
            s += p;
            n = fmaf(p, msg, n);
        }
    }
    float agg = n / fmaxf(s, 1e-16f);  // 0 for isolated nodes
    float xv = h2in[(size_t)node * HD + lane] + agg;

    float acc = b[lane];
    #pragma unroll
    for (int k = 0; k < 64; k++) acc = fmaf(rl(xv, k), Ws[k * HD + lane], acc);
    if (hres) acc += hres[(size_t)node * HD + lane];
    hout[(size_t)node * HD + lane] = acc;

    // fused prenorm for the next layer: h2out = relu(LN(acc))
    if (h2out) {
        float ssum = acc;
        #pragma unroll
        for (int d = 32; d; d >>= 1) ssum += __shfl_xor(ssum, d);
        float mu = ssum * (1.f / 64.f);
        float dd = acc - mu;
        float q = dd * dd;
        #pragma unroll
        for (int d = 32; d; d >>= 1) q += __shfl_xor(q, d);
        float inv = rsqrtf(q * (1.f / 64.f) + 1e-5f);
        float y = dd * inv * gnext[lane] + bnext[lane];
        h2out[(size_t)node * HD + lane] = fmaxf(y, 0.f);
    }
}

// ---------------- Predictor: out = h @ pred_W + pred_b ----------------

__global__ __launch_bounds__(256) void k_pred(const float* __restrict__ h,
                                              const float* __restrict__ W,
                                              const float* __restrict__ b,
                                              float* __restrict__ out) {
    __shared__ float Ws[HD * OUTD];  // 28 KB
    int tid = threadIdx.x;
    for (int i = tid; i < HD * OUTD; i += 256) Ws[i] = W[i];
    __syncthreads();
    int lane = tid & 63, w = tid >> 6;
    int node = blockIdx.x * 4 + w;
    float x = h[(size_t)node * HD + lane];
    float a0 = b[lane];
    float a1 = (lane < OUTD - 64) ? b[64 + lane] : 0.f;
    #pragma unroll
    for (int k = 0; k < 64; k++) {
        float xk = rl(x, k);
        a0 = fmaf(xk, Ws[k * OUTD + lane], a0);
        if (lane < OUTD - 64) a1 = fmaf(xk, Ws[k * OUTD + 64 + lane], a1);
    }
    out[(size_t)node * OUTD + lane] = a0;
    if (lane < OUTD - 64) out[(size_t)node * OUTD + 64 + lane] = a1;
}

// ---------------- Launch ----------------

extern "C" void kernel_launch(void* const* d_in, const int* in_sizes, int n_in,
                              void* d_out, int out_size, void* d_ws, size_t ws_size,
                              hipStream_t stream) {
    const float* x    = (const float*)d_in[0];
    const int*   ei   = (const int*)d_in[1];
    const float* encW = (const float*)d_in[2];
    const float* encb = (const float*)d_in[3];
    const float* lng  = (const float*)d_in[4];
    const float* lnb  = (const float*)d_in[5];
    const float* mlpW = (const float*)d_in[6];
    const float* mlpb = (const float*)d_in[7];
    const float* pW   = (const float*)d_in[8];
    const float* pb   = (const float*)d_in[9];
    float* out = (float*)d_out;

    float* hA  = (float*)d_ws;
    float* hB  = hA + (size_t)NN * HD;
    float* h2A = hB + (size_t)NN * HD;
    float* h2B = h2A + (size_t)NN * HD;
    int* rp   = (int*)(h2B + (size_t)NN * HD);
    int* cur  = rp + (NN + 1);
    int* csrc = cur + NN;
    int* bsum = csrc + EE;
    int* boff = bsum + 64;

    // CSR build (per call; ws is re-poisoned each launch)
    hipMemsetAsync(cur, 0, NN * sizeof(int), stream);
    k_hist<<<(EE + 255) / 256, 256, 0, stream>>>(ei, cur);
    const int NB = (NN + 1023) / 1024;  // 49
    k_scan1<<<NB, 1024, 0, stream>>>(cur, rp, bsum);
    k_scan2<<<1, 64, 0, stream>>>(bsum, boff, NB);
    k_scan3<<<NB, 1024, 0, stream>>>(rp, cur, boff);
    k_scatter<<<(EE + 255) / 256, 256, 0, stream>>>(ei, cur, csrc);

    // Encoder -> h_0 in hA
    k_enc<<<NN / 4, 256, 0, stream>>>(x, encW, encb, hA);

    // Layer 0: gin = h_0 (no prenorm, no residual); writes h_1 -> hB,
    // and fused prenorm(g[0],b[0]) -> h2A for layer 1.
    k_layer<<<NN / 4, 256, 0, stream>>>(hA, nullptr, hB, h2A, rp, csrc,
                                        mlpW, mlpb, lng, lnb);

    float* hres = hB;   // h_1
    float* hdst = hA;
    float* gcur = h2A;
    float* gnxt = h2B;
    for (int l = 1; l < LL; ++l) {
        bool last = (l == LL - 1);
        k_layer<<<NN / 4, 256, 0, stream>>>(gcur, hres, hdst,
                                            last ? nullptr : gnxt,
                                            rp, csrc,
                                            mlpW + (size_t)l * HD * HD,
                                            mlpb + (size_t)l * HD,
                                            last ? nullptr : lng + (size_t)l * HD,
                                            last ? nullptr : lnb + (size_t)l * HD);
        float* t = hres; hres = hdst; hdst = t;
        t = gcur; gcur = gnxt; gnxt = t;
    }

    // Predictor on h_14 (= hres after final swap)
    k_pred<<<NN / 4, 256, 0, stream>>>(hres, pW, pb, out);
}

// Round 5
// 809.169 us; speedup vs baseline: 2.5185x; 1.1602x over previous
//
#include <hip/hip_runtime.h>
#include <hip/hip_bf16.h>

#define NN 50000
#define EE 800000
#define HD 64
#define LL 14
#define IND 128
#define OUTD 112

typedef __attribute__((ext_vector_type(8))) short short8;
typedef __attribute__((ext_vector_type(4))) float float4_;

__device__ __forceinline__ short bf16_hi(float x) {
    return (short)(__float_as_uint(x) >> 16);  // truncation split
}
__device__ __forceinline__ float bf16_f(short s) {
    return __uint_as_float(((unsigned)(unsigned short)s) << 16);
}

// split 8 consecutive fp32 (16B-aligned) into bf16 hi/lo fragments
__device__ __forceinline__ void split8(const float* p, short8& hi, short8& lo) {
    float4_ a = *(const float4_*)p;
    float4_ b = *(const float4_*)(p + 4);
    float v[8] = {a[0], a[1], a[2], a[3], b[0], b[1], b[2], b[3]};
    #pragma unroll
    for (int j = 0; j < 8; ++j) {
        short h = bf16_hi(v[j]);
        hi[j] = h;
        lo[j] = bf16_hi(v[j] - bf16_f(h));
    }
}

// load B-fragment (8 k-rows of one 16-col slice) from global weights, hi/lo split
__device__ __forceinline__ void load_b(const float* __restrict__ W, int ldw,
                                       int colbase, int krow, short8& hi, short8& lo) {
    #pragma unroll
    for (int j = 0; j < 8; ++j) {
        float wv = W[(size_t)(krow + j) * ldw + colbase];
        short h = bf16_hi(wv);
        hi[j] = h;
        lo[j] = bf16_hi(wv - bf16_f(h));
    }
}

// fp32-accurate product via 3 bf16 MFMAs (drop lo*lo)
__device__ __forceinline__ float4_ mm3(short8 ah, short8 al, short8 bh, short8 bl,
                                       float4_ acc) {
    acc = __builtin_amdgcn_mfma_f32_16x16x32_bf16(ah, bh, acc, 0, 0, 0);
    acc = __builtin_amdgcn_mfma_f32_16x16x32_bf16(al, bh, acc, 0, 0, 0);
    acc = __builtin_amdgcn_mfma_f32_16x16x32_bf16(ah, bl, acc, 0, 0, 0);
    return acc;
}

// ---------------- CSR build ----------------

__global__ void k_hist(const int* __restrict__ ei, int* __restrict__ deg) {
    int e = blockIdx.x * blockDim.x + threadIdx.x;
    if (e < EE) atomicAdd(&deg[ei[EE + e]], 1);
}

__global__ __launch_bounds__(1024) void k_scan1(const int* __restrict__ deg,
                                                int* __restrict__ excl,
                                                int* __restrict__ bsum) {
    __shared__ int ws[16];
    int tid = threadIdx.x, lane = tid & 63, w = tid >> 6;
    int gid = blockIdx.x * 1024 + tid;
    int v = (gid < NN) ? deg[gid] : 0;
    int x = v;
    #pragma unroll
    for (int d = 1; d < 64; d <<= 1) {
        int y = __shfl_up(x, d);
        if (lane >= d) x += y;
    }
    if (lane == 63) ws[w] = x;
    __syncthreads();
    if (tid == 0) {
        int acc = 0;
        for (int i = 0; i < 16; i++) { int t = ws[i]; ws[i] = acc; acc += t; }
        bsum[blockIdx.x] = acc;
    }
    __syncthreads();
    if (gid < NN) excl[gid] = x - v + ws[w];
}

__global__ void k_scan2(const int* __restrict__ bsum, int* __restrict__ boff, int nb) {
    if (threadIdx.x == 0) {
        int acc = 0;
        for (int i = 0; i < nb; i++) { boff[i] = acc; acc += bsum[i]; }
    }
}

__global__ __launch_bounds__(1024) void k_scan3(int* __restrict__ rp, int* __restrict__ cur,
                                                const int* __restrict__ boff) {
    int gid = blockIdx.x * 1024 + threadIdx.x;
    if (gid < NN) {
        int v = rp[gid] + boff[blockIdx.x];
        rp[gid] = v;
        cur[gid] = v;
    }
    if (gid == 0) rp[NN] = EE;
}

__global__ void k_scatter(const int* __restrict__ ei, int* __restrict__ cur,
                          int* __restrict__ csrc) {
    int e = blockIdx.x * blockDim.x + threadIdx.x;
    if (e < EE) {
        int d = ei[EE + e];
        int pos = atomicAdd(&cur[d], 1);
        csrc[pos] = ei[e];
    }
}

// ---------------- Encoder: h = x @ enc_W + enc_b  (MFMA, 16 nodes/block) ----------------

__global__ __launch_bounds__(256) void k_enc(const float* __restrict__ x,
                                             const float* __restrict__ W,
                                             const float* __restrict__ b,
                                             float* __restrict__ h) {
    __shared__ float X[16 * 132];  // 16 nodes x 128 ch, stride 132 (pad)
    int tid = threadIdx.x, lane = tid & 63, w = tid >> 6;
    int nb = blockIdx.x * 16;
    int nq = lane >> 4, nr = lane & 15;
    int colbase = w * 16 + nr;

    // stage x tile: thread reads 8 consecutive floats
    {
        const float* src = x + (size_t)nb * IND + tid * 8;
        float4_ a = *(const float4_*)src;
        float4_ c = *(const float4_*)(src + 4);
        int m = tid >> 4, k8 = 8 * (tid & 15);
        *(float4_*)&X[m * 132 + k8] = a;
        *(float4_*)&X[m * 132 + k8 + 4] = c;
    }
    __syncthreads();

    float4_ acc = {};
    #pragma unroll
    for (int t = 0; t < 4; ++t) {
        short8 ah, al, bh, bl;
        split8(&X[nr * 132 + t * 32 + nq * 8], ah, al);
        load_b(W, HD, colbase, t * 32 + nq * 8, bh, bl);
        acc = mm3(ah, al, bh, bl, acc);
    }

    float bias = b[colbase];
    #pragma unroll
    for (int r = 0; r < 4; ++r) {
        int node = nb + nq * 4 + r;
        h[(size_t)node * HD + colbase] = acc[r] + bias;
    }
}

// ---------------- GENConv layer: softmax agg + MFMA matmul + residual
//                  + fused next-layer prenorm ----------------

__global__ __launch_bounds__(256) void k_layer(const float* __restrict__ gin,
                                               const float* __restrict__ hres,
                                               float* __restrict__ hout,
                                               float* __restrict__ h2out,
                                               const int* __restrict__ rp,
                                               const int* __restrict__ csrc,
                                               const float* __restrict__ W,
                                               const float* __restrict__ b,
                                               const float* __restrict__ gnext,
                                               const float* __restrict__ bnext) {
    __shared__ float T[16 * 68];  // xv tile, reused as C tile (4.25 KB)
    int tid = threadIdx.x, lane = tid & 63, w = tid >> 6;
    int nb = blockIdx.x * 16;
    int nq = lane >> 4, nr = lane & 15;
    int colbase = w * 16 + nr;

    // B fragments (this wave's 16-col slice of W), register-resident
    short8 Bhi[2], Blo[2];
    #pragma unroll
    for (int t = 0; t < 2; ++t)
        load_b(W, HD, colbase, t * 32 + nq * 8, Bhi[t], Blo[t]);

    // gather: 4 nodes per wave; msg bounded -> no running max needed
    #pragma unroll 1
    for (int i = 0; i < 4; ++i) {
        int node = nb + w * 4 + i;
        int beg = rp[node], end = rp[node + 1], deg = end - beg;
        float s = 0.f, n = 0.f;
        for (int chunk = 0; chunk < deg; chunk += 64) {
            int cnt = min(64, deg - chunk);
            int myidx = 0;
            if (chunk + lane < deg) myidx = csrc[beg + chunk + lane];
            int k = 0;
            for (; k + 8 <= cnt; k += 8) {
                #pragma unroll
                for (int j = 0; j < 8; ++j) {
                    int src = __builtin_amdgcn_readlane(myidx, k + j);
                    float v = gin[(size_t)src * HD + lane];
                    float msg = fminf(fmaxf(v, 0.f) + 1e-7f, 50.f);
                    float p = __expf(msg);
                    s += p;
                    n = fmaf(p, msg, n);
                }
            }
            for (; k < cnt; ++k) {
                int src = __builtin_amdgcn_readlane(myidx, k);
                float v = gin[(size_t)src * HD + lane];
                float msg = fminf(fmaxf(v, 0.f) + 1e-7f, 50.f);
                float p = __expf(msg);
                s += p;
                n = fmaf(p, msg, n);
            }
        }
        float agg = n / fmaxf(s, 1e-16f);
        float xv = gin[(size_t)node * HD + lane] + agg;
        T[(w * 4 + i) * 68 + lane] = xv;
    }
    __syncthreads();

    // A fragments for all 16 nodes (lane's node = nr)
    short8 Ahi[2], Alo[2];
    #pragma unroll
    for (int t = 0; t < 2; ++t)
        split8(&T[nr * 68 + t * 32 + nq * 8], Ahi[t], Alo[t]);
    __syncthreads();  // all A reads done before T is overwritten

    float4_ acc = {};
    #pragma unroll
    for (int t = 0; t < 2; ++t)
        acc = mm3(Ahi[t], Alo[t], Bhi[t], Blo[t], acc);

    // epilogue: C[m = nq*4+r][col = colbase]; + bias + residual
    float bias = b[colbase];
    #pragma unroll
    for (int r = 0; r < 4; ++r) {
        int m = nq * 4 + r;
        int node = nb + m;
        float v = acc[r] + bias;
        if (hres) v += hres[(size_t)node * HD + colbase];
        hout[(size_t)node * HD + colbase] = v;
        T[m * 68 + colbase] = v;
    }
    if (!h2out) return;
    __syncthreads();

    // LN phase: thread -> node tid>>4, 4 channels per thread
    int m = tid >> 4, c4 = (tid & 15) * 4;
    float4_ vv = *(const float4_*)&T[m * 68 + c4];
    float ps = (vv[0] + vv[1]) + (vv[2] + vv[3]);
    float pq = (vv[0] * vv[0] + vv[1] * vv[1]) + (vv[2] * vv[2] + vv[3] * vv[3]);
    #pragma unroll
    for (int d = 8; d; d >>= 1) {
        ps += __shfl_xor(ps, d);
        pq += __shfl_xor(pq, d);
    }
    float mu = ps * (1.f / 64.f);
    float var = pq * (1.f / 64.f) - mu * mu;
    float inv = rsqrtf(fmaxf(var, 0.f) + 1e-5f);
    float4_ g4 = *(const float4_*)&gnext[c4];
    float4_ b4 = *(const float4_*)&bnext[c4];
    float4_ y;
    #pragma unroll
    for (int j = 0; j < 4; ++j)
        y[j] = fmaxf((vv[j] - mu) * inv * g4[j] + b4[j], 0.f);
    *(float4_*)&h2out[(size_t)(nb + m) * HD + c4] = y;
}

// ---------------- Predictor: out = h @ pred_W + pred_b  (MFMA) ----------------

__global__ __launch_bounds__(256) void k_pred(const float* __restrict__ h,
                                              const float* __restrict__ W,
                                              const float* __restrict__ b,
                                              float* __restrict__ out) {
    __shared__ float T[16 * 68];
    int tid = threadIdx.x, lane = tid & 63, w = tid >> 6;
    int nb = blockIdx.x * 16;
    int nq = lane >> 4, nr = lane & 15;

    // stage h tile (16 nodes x 64 ch): 4 floats per thread
    {
        const float* src = h + (size_t)nb * HD + tid * 4;
        float4_ a = *(const float4_*)src;
        int m = tid >> 4, k4 = 4 * (tid & 15);
        *(float4_*)&T[m * 68 + k4] = a;
    }
    __syncthreads();

    short8 Ahi[2], Alo[2];
    #pragma unroll
    for (int t = 0; t < 2; ++t)
        split8(&T[nr * 68 + t * 32 + nq * 8], Ahi[t], Alo[t]);

    // col tiles: wave w covers tiles {w, w+4} (7 tiles of 16 cols = 112)
    for (int tt = w; tt < 7; tt += 4) {
        int colbase = tt * 16 + nr;
        float4_ acc = {};
        #pragma unroll
        for (int t = 0; t < 2; ++t) {
            short8 bh, bl;
            load_b(W, OUTD, colbase, t * 32 + nq * 8, bh, bl);
            acc = mm3(Ahi[t], Alo[t], bh, bl, acc);
        }
        float bias = b[colbase];
        #pragma unroll
        for (int r = 0; r < 4; ++r) {
            int node = nb + nq * 4 + r;
            out[(size_t)node * OUTD + colbase] = acc[r] + bias;
        }
    }
}

// ---------------- Launch ----------------

extern "C" void kernel_launch(void* const* d_in, const int* in_sizes, int n_in,
                              void* d_out, int out_size, void* d_ws, size_t ws_size,
                              hipStream_t stream) {
    const float* x    = (const float*)d_in[0];
    const int*   ei   = (const int*)d_in[1];
    const float* encW = (const float*)d_in[2];
    const float* encb = (const float*)d_in[3];
    const float* lng  = (const float*)d_in[4];
    const float* lnb  = (const float*)d_in[5];
    const float* mlpW = (const float*)d_in[6];
    const float* mlpb = (const float*)d_in[7];
    const float* pW   = (const float*)d_in[8];
    const float* pb   = (const float*)d_in[9];
    float* out = (float*)d_out;

    float* hA  = (float*)d_ws;
    float* hB  = hA + (size_t)NN * HD;
    float* h2A = hB + (size_t)NN * HD;
    float* h2B = h2A + (size_t)NN * HD;
    int* rp   = (int*)(h2B + (size_t)NN * HD);
    int* cur  = rp + (NN + 1);
    int* csrc = cur + NN;
    int* bsum = csrc + EE;
    int* boff = bsum + 64;

    // CSR build (per call; ws is re-poisoned each launch)
    hipMemsetAsync(cur, 0, NN * sizeof(int), stream);
    k_hist<<<(EE + 255) / 256, 256, 0, stream>>>(ei, cur);
    const int NB = (NN + 1023) / 1024;  // 49
    k_scan1<<<NB, 1024, 0, stream>>>(cur, rp, bsum);
    k_scan2<<<1, 64, 0, stream>>>(bsum, boff, NB);
    k_scan3<<<NB, 1024, 0, stream>>>(rp, cur, boff);
    k_scatter<<<(EE + 255) / 256, 256, 0, stream>>>(ei, cur, csrc);

    // Encoder -> h_0 in hA
    k_enc<<<NN / 16, 256, 0, stream>>>(x, encW, encb, hA);

    // Layer 0: gin = h_0 (no prenorm, no residual); writes h_1 -> hB,
    // fused prenorm(g[0],b[0]) -> h2A for layer 1.
    k_layer<<<NN / 16, 256, 0, stream>>>(hA, nullptr, hB, h2A, rp, csrc,
                                         mlpW, mlpb, lng, lnb);

    float* hres = hB;   // h_1
    float* hdst = hA;
    float* gcur = h2A;
    float* gnxt = h2B;
    for (int l = 1; l < LL; ++l) {
        bool last = (l == LL - 1);
        k_layer<<<NN / 16, 256, 0, stream>>>(gcur, hres, hdst,
                                             last ? nullptr : gnxt,
                                             rp, csrc,
                                             mlpW + (size_t)l * HD * HD,
                                             mlpb + (size_t)l * HD,
                                             last ? nullptr : lng + (size_t)l * HD,
                                             last ? nullptr : lnb + (size_t)l * HD);
        float* t = hres; hres = hdst; hdst = t;
        t = gcur; gcur = gnxt; gnxt = t;
    }

    // Predictor on h_14
    k_pred<<<NN / 16, 256, 0, stream>>>(hres, pW, pb, out);
}

// Round 6
// 774.067 us; speedup vs baseline: 2.6327x; 1.0453x over previous
//
#include <hip/hip_runtime.h>
#include <hip/hip_bf16.h>

#define NN 50000
#define EE 800000
#define HD 64
#define LL 14
#define IND 128
#define OUTD 112

typedef __attribute__((ext_vector_type(8))) short short8;
typedef __attribute__((ext_vector_type(4))) float float4_;
typedef __attribute__((ext_vector_type(4))) unsigned uint4_;

__device__ __forceinline__ short bf16_hi(float x) {
    return (short)(__float_as_uint(x) >> 16);  // truncation split
}
__device__ __forceinline__ float bf16_f(short s) {
    return __uint_as_float(((unsigned)(unsigned short)s) << 16);
}
// round-to-nearest-even fp32 -> bf16 bits
__device__ __forceinline__ unsigned short f2b_rne(float x) {
    unsigned u = __float_as_uint(x);
    u += 0x7fffu + ((u >> 16) & 1u);
    return (unsigned short)(u >> 16);
}
// pack P (low) and Q (high) as bf16
__device__ __forceinline__ unsigned packPQ(float P, float Q) {
    return ((unsigned)f2b_rne(Q) << 16) | (unsigned)f2b_rne(P);
}

// split 8 consecutive fp32 (16B-aligned) into bf16 hi/lo fragments
__device__ __forceinline__ void split8(const float* p, short8& hi, short8& lo) {
    float4_ a = *(const float4_*)p;
    float4_ b = *(const float4_*)(p + 4);
    float v[8] = {a[0], a[1], a[2], a[3], b[0], b[1], b[2], b[3]};
    #pragma unroll
    for (int j = 0; j < 8; ++j) {
        short h = bf16_hi(v[j]);
        hi[j] = h;
        lo[j] = bf16_hi(v[j] - bf16_f(h));
    }
}

// load B-fragment (8 k-rows of one 16-col slice) from global weights, hi/lo split
__device__ __forceinline__ void load_b(const float* __restrict__ W, int ldw,
                                       int colbase, int krow, short8& hi, short8& lo) {
    #pragma unroll
    for (int j = 0; j < 8; ++j) {
        float wv = W[(krow + j) * ldw + colbase];
        short h = bf16_hi(wv);
        hi[j] = h;
        lo[j] = bf16_hi(wv - bf16_f(h));
    }
}

// fp32-accurate product via 3 bf16 MFMAs (drop lo*lo)
__device__ __forceinline__ float4_ mm3(short8 ah, short8 al, short8 bh, short8 bl,
                                       float4_ acc) {
    acc = __builtin_amdgcn_mfma_f32_16x16x32_bf16(ah, bh, acc, 0, 0, 0);
    acc = __builtin_amdgcn_mfma_f32_16x16x32_bf16(al, bh, acc, 0, 0, 0);
    acc = __builtin_amdgcn_mfma_f32_16x16x32_bf16(ah, bl, acc, 0, 0, 0);
    return acc;
}

// ---------------- CSR build ----------------

// rank capture: rank[e] = within-dst arrival order; cnt[dst] = degree
__global__ void k_hist(const int* __restrict__ ei, int* __restrict__ cnt,
                       int* __restrict__ rank) {
    int e = blockIdx.x * blockDim.x + threadIdx.x;
    if (e < EE) rank[e] = atomicAdd(&cnt[ei[EE + e]], 1);
}

__global__ __launch_bounds__(1024) void k_scan1(const int* __restrict__ deg,
                                                int* __restrict__ excl,
                                                int* __restrict__ bsum) {
    __shared__ int ws[16];
    int tid = threadIdx.x, lane = tid & 63, w = tid >> 6;
    int gid = blockIdx.x * 1024 + tid;
    int v = (gid < NN) ? deg[gid] : 0;
    int x = v;
    #pragma unroll
    for (int d = 1; d < 64; d <<= 1) {
        int y = __shfl_up(x, d);
        if (lane >= d) x += y;
    }
    if (lane == 63) ws[w] = x;
    __syncthreads();
    if (tid == 0) {
        int acc = 0;
        for (int i = 0; i < 16; i++) { int t = ws[i]; ws[i] = acc; acc += t; }
        bsum[blockIdx.x] = acc;
    }
    __syncthreads();
    if (gid < NN) excl[gid] = x - v + ws[w];
}

__global__ void k_scan2(const int* __restrict__ bsum, int* __restrict__ boff, int nb) {
    if (threadIdx.x == 0) {
        int acc = 0;
        for (int i = 0; i < nb; i++) { boff[i] = acc; acc += bsum[i]; }
    }
}

__global__ __launch_bounds__(1024) void k_scan3(int* __restrict__ rp,
                                                const int* __restrict__ boff) {
    int gid = blockIdx.x * 1024 + threadIdx.x;
    if (gid < NN) rp[gid] += boff[blockIdx.x];
    if (gid == 0) rp[NN] = EE;
}

// atomic-free scatter: position = rp[dst] + rank[e]
__global__ void k_scatter(const int* __restrict__ ei, const int* __restrict__ rp,
                          const int* __restrict__ rank, int* __restrict__ csrc) {
    int e = blockIdx.x * blockDim.x + threadIdx.x;
    if (e < EE) {
        int d = ei[EE + e];
        csrc[rp[d] + rank[e]] = ei[e];
    }
}

// ---------------- Encoder: h0 = x @ enc_W + enc_b, plus PQ0 ----------------

__global__ __launch_bounds__(256) void k_enc(const float* __restrict__ x,
                                             const float* __restrict__ W,
                                             const float* __restrict__ b,
                                             float* __restrict__ h,
                                             unsigned* __restrict__ PQ0) {
    __shared__ float X[16 * 132];  // 16 nodes x 128 ch, stride 132 (pad)
    int tid = threadIdx.x, lane = tid & 63, w = tid >> 6;
    int nb = blockIdx.x * 16;
    int nq = lane >> 4, nr = lane & 15;
    int colbase = w * 16 + nr;

    {
        const float* src = x + (size_t)nb * IND + tid * 8;
        float4_ a = *(const float4_*)src;
        float4_ c = *(const float4_*)(src + 4);
        int m = tid >> 4, k8 = 8 * (tid & 15);
        *(float4_*)&X[m * 132 + k8] = a;
        *(float4_*)&X[m * 132 + k8 + 4] = c;
    }
    __syncthreads();

    float4_ acc = {};
    #pragma unroll
    for (int t = 0; t < 4; ++t) {
        short8 ah, al, bh, bl;
        split8(&X[nr * 132 + t * 32 + nq * 8], ah, al);
        load_b(W, HD, colbase, t * 32 + nq * 8, bh, bl);
        acc = mm3(ah, al, bh, bl, acc);
    }

    float bias = b[colbase];
    #pragma unroll
    for (int r = 0; r < 4; ++r) {
        int node = nb + nq * 4 + r;
        float y = acc[r] + bias;
        h[node * HD + colbase] = y;
        float msg = fminf(fmaxf(y, 0.f) + 1e-7f, 50.f);
        float P = __expf(msg);
        PQ0[node * HD + colbase] = packPQ(P, P * msg);
    }
}

// ---------------- GENConv layer: PQ-gather softmax agg + MFMA matmul + residual
//                  + fused next-layer prenorm -> PQout ----------------

__global__ __launch_bounds__(256) void k_layer(const unsigned* __restrict__ PQin,
                                               const float* __restrict__ selfh,  // layer0 only
                                               const float* __restrict__ hres,
                                               float* __restrict__ hout,
                                               unsigned* __restrict__ PQout,
                                               const int* __restrict__ rp,
                                               const int* __restrict__ csrc,
                                               const float* __restrict__ W,
                                               const float* __restrict__ b,
                                               const float* __restrict__ gnext,
                                               const float* __restrict__ bnext) {
    __shared__ float T[16 * 68];  // xv tile, reused as C tile (4.25 KB)
    int tid = threadIdx.x, lane = tid & 63, w = tid >> 6;
    int nb = blockIdx.x * 16;
    int nq = lane >> 4, nr = lane & 15;
    int colbase = w * 16 + nr;

    // B fragments (this wave's 16-col slice of W), register-resident
    short8 Bhi[2], Blo[2];
    #pragma unroll
    for (int t = 0; t < 2; ++t)
        load_b(W, HD, colbase, t * 32 + nq * 8, Bhi[t], Blo[t]);

    // gather: 4 nodes per wave; P,Q precomputed per src node (bf16x2 packed)
    #pragma unroll 1
    for (int i = 0; i < 4; ++i) {
        int node = nb + w * 4 + i;
        int beg = rp[node], end = rp[node + 1], deg = end - beg;
        float s = 0.f, n = 0.f;
        for (int chunk = 0; chunk < deg; chunk += 64) {
            int cnt = min(64, deg - chunk);
            int myidx = 0;
            if (chunk + lane < deg) myidx = csrc[beg + chunk + lane];
            int k = 0;
            for (; k + 8 <= cnt; k += 8) {
                #pragma unroll
                for (int j = 0; j < 8; ++j) {
                    int src = __builtin_amdgcn_readlane(myidx, k + j);
                    unsigned pq = PQin[src * HD + lane];
                    s += __uint_as_float(pq << 16);
                    n += __uint_as_float(pq & 0xffff0000u);
                }
            }
            for (; k < cnt; ++k) {
                int src = __builtin_amdgcn_readlane(myidx, k);
                unsigned pq = PQin[src * HD + lane];
                s += __uint_as_float(pq << 16);
                n += __uint_as_float(pq & 0xffff0000u);
            }
        }
        float agg = n / fmaxf(s, 1e-16f);  // 0 for isolated nodes
        float xv;
        if (selfh) {
            xv = selfh[node * HD + lane] + agg;  // layer 0: raw h0 (can be <0)
        } else {
            unsigned pq = PQin[node * HD + lane];
            float Ps = __uint_as_float(pq << 16);
            float Qs = __uint_as_float(pq & 0xffff0000u);
            xv = __fdividef(Qs, Ps) - 1e-7f + agg;  // y = msg - eps (y>=0 here)
        }
        T[(w * 4 + i) * 68 + lane] = xv;
    }
    __syncthreads();

    // A fragments for all 16 nodes (lane's node = nr)
    short8 Ahi[2], Alo[2];
    #pragma unroll
    for (int t = 0; t < 2; ++t)
        split8(&T[nr * 68 + t * 32 + nq * 8], Ahi[t], Alo[t]);
    __syncthreads();  // all A reads done before T is overwritten

    float4_ acc = {};
    #pragma unroll
    for (int t = 0; t < 2; ++t)
        acc = mm3(Ahi[t], Alo[t], Bhi[t], Blo[t], acc);

    // epilogue: C[m = nq*4+r][col = colbase]; + bias + residual
    float bias = b[colbase];
    #pragma unroll
    for (int r = 0; r < 4; ++r) {
        int m = nq * 4 + r;
        int node = nb + m;
        float v = acc[r] + bias;
        if (hres) v += hres[node * HD + colbase];
        hout[node * HD + colbase] = v;
        T[m * 68 + colbase] = v;
    }
    if (!PQout) return;
    __syncthreads();

    // LN phase: thread -> node tid>>4, 4 channels per thread; emit PQout
    int m = tid >> 4, c4 = (tid & 15) * 4;
    float4_ vv = *(const float4_*)&T[m * 68 + c4];
    float ps = (vv[0] + vv[1]) + (vv[2] + vv[3]);
    float pq_ = (vv[0] * vv[0] + vv[1] * vv[1]) + (vv[2] * vv[2] + vv[3] * vv[3]);
    #pragma unroll
    for (int d = 8; d; d >>= 1) {
        ps += __shfl_xor(ps, d);
        pq_ += __shfl_xor(pq_, d);
    }
    float mu = ps * (1.f / 64.f);
    float var = pq_ * (1.f / 64.f) - mu * mu;
    float inv = rsqrtf(fmaxf(var, 0.f) + 1e-5f);
    float4_ g4 = *(const float4_*)&gnext[c4];
    float4_ b4 = *(const float4_*)&bnext[c4];
    uint4_ pqo;
    #pragma unroll
    for (int j = 0; j < 4; ++j) {
        float y = fmaxf((vv[j] - mu) * inv * g4[j] + b4[j], 0.f);
        float msg = fminf(y + 1e-7f, 50.f);
        float P = __expf(msg);
        pqo[j] = packPQ(P, P * msg);
    }
    *(uint4_*)&PQout[(nb + m) * HD + c4] = pqo;
}

// ---------------- Predictor: out = h @ pred_W + pred_b  (MFMA) ----------------

__global__ __launch_bounds__(256) void k_pred(const float* __restrict__ h,
                                              const float* __restrict__ W,
                                              const float* __restrict__ b,
                                              float* __restrict__ out) {
    __shared__ float T[16 * 68];
    int tid = threadIdx.x, lane = tid & 63, w = tid >> 6;
    int nb = blockIdx.x * 16;
    int nq = lane >> 4, nr = lane & 15;

    {
        const float* src = h + (size_t)nb * HD + tid * 4;
        float4_ a = *(const float4_*)src;
        int m = tid >> 4, k4 = 4 * (tid & 15);
        *(float4_*)&T[m * 68 + k4] = a;
    }
    __syncthreads();

    short8 Ahi[2], Alo[2];
    #pragma unroll
    for (int t = 0; t < 2; ++t)
        split8(&T[nr * 68 + t * 32 + nq * 8], Ahi[t], Alo[t]);

    for (int tt = w; tt < 7; tt += 4) {
        int colbase = tt * 16 + nr;
        float4_ acc = {};
        #pragma unroll
        for (int t = 0; t < 2; ++t) {
            short8 bh, bl;
            load_b(W, OUTD, colbase, t * 32 + nq * 8, bh, bl);
            acc = mm3(Ahi[t], Alo[t], bh, bl, acc);
        }
        float bias = b[colbase];
        #pragma unroll
        for (int r = 0; r < 4; ++r) {
            int node = nb + nq * 4 + r;
            out[node * OUTD + colbase] = acc[r] + bias;
        }
    }
}

// ---------------- Launch ----------------

extern "C" void kernel_launch(void* const* d_in, const int* in_sizes, int n_in,
                              void* d_out, int out_size, void* d_ws, size_t ws_size,
                              hipStream_t stream) {
    const float* x    = (const float*)d_in[0];
    const int*   ei   = (const int*)d_in[1];
    const float* encW = (const float*)d_in[2];
    const float* encb = (const float*)d_in[3];
    const float* lng  = (const float*)d_in[4];
    const float* lnb  = (const float*)d_in[5];
    const float* mlpW = (const float*)d_in[6];
    const float* mlpb = (const float*)d_in[7];
    const float* pW   = (const float*)d_in[8];
    const float* pb   = (const float*)d_in[9];
    float* out = (float*)d_out;

    float* hA  = (float*)d_ws;
    float* hB  = hA + (size_t)NN * HD;
    unsigned* PQA = (unsigned*)(hB + (size_t)NN * HD);
    unsigned* PQB = PQA + (size_t)NN * HD;
    int* rp   = (int*)(PQB + (size_t)NN * HD);
    int* cnt  = rp + (NN + 1);
    int* csrc = cnt + NN;
    int* rank = csrc + EE;
    int* bsum = rank + EE;
    int* boff = bsum + 64;

    // CSR build (per call; ws is re-poisoned each launch)
    hipMemsetAsync(cnt, 0, NN * sizeof(int), stream);
    k_hist<<<(EE + 255) / 256, 256, 0, stream>>>(ei, cnt, rank);
    const int NB = (NN + 1023) / 1024;  // 49
    k_scan1<<<NB, 1024, 0, stream>>>(cnt, rp, bsum);
    k_scan2<<<1, 64, 0, stream>>>(bsum, boff, NB);
    k_scan3<<<NB, 1024, 0, stream>>>(rp, boff);
    k_scatter<<<(EE + 255) / 256, 256, 0, stream>>>(ei, rp, rank, csrc);

    // Encoder -> h_0 in hA, PQ_0 in PQA
    k_enc<<<NN / 16, 256, 0, stream>>>(x, encW, encb, hA, PQA);

    // Layer 0: self term = raw h0; writes h_1 -> hB, PQ_1 -> PQB
    k_layer<<<NN / 16, 256, 0, stream>>>(PQA, hA, nullptr, hB, PQB, rp, csrc,
                                         mlpW, mlpb, lng, lnb);

    float* hres = hB;   // h_1
    float* hdst = hA;
    unsigned* pqc = PQB;
    unsigned* pqn = PQA;
    for (int l = 1; l < LL; ++l) {
        bool last = (l == LL - 1);
        k_layer<<<NN / 16, 256, 0, stream>>>(pqc, nullptr, hres, hdst,
                                             last ? nullptr : pqn,
                                             rp, csrc,
                                             mlpW + (size_t)l * HD * HD,
                                             mlpb + (size_t)l * HD,
                                             last ? nullptr : lng + (size_t)l * HD,
                                             last ? nullptr : lnb + (size_t)l * HD);
        float* t = hres; hres = hdst; hdst = t;
        unsigned* u = pqc; pqc = pqn; pqn = u;
    }

    // Predictor on h_14
    k_pred<<<NN / 16, 256, 0, stream>>>(hres, pW, pb, out);
}

// Round 7
// 757.380 us; speedup vs baseline: 2.6907x; 1.0220x over previous
//
#include <hip/hip_runtime.h>
#include <hip/hip_bf16.h>

#define NN 50000
#define EE 800000
#define HD 64
#define LL 14
#define IND 128
#define OUTD 112
#define LN2 0.69314718056f

typedef __attribute__((ext_vector_type(8))) short short8;
typedef __attribute__((ext_vector_type(4))) float float4_;
typedef __attribute__((ext_vector_type(4))) unsigned short ushort4_;

__device__ __forceinline__ short bf16_hi(float x) {
    return (short)(__float_as_uint(x) >> 16);  // truncation split
}
__device__ __forceinline__ float bf16_f(short s) {
    return __uint_as_float(((unsigned)(unsigned short)s) << 16);
}
__device__ __forceinline__ float us2f(unsigned short u) {
    return __uint_as_float(((unsigned)u) << 16);
}
// round-to-nearest-even fp32 -> bf16 bits
__device__ __forceinline__ unsigned short f2b_rne(float x) {
    unsigned u = __float_as_uint(x);
    u += 0x7fffu + ((u >> 16) & 1u);
    return (unsigned short)(u >> 16);
}

// split 8 consecutive fp32 (16B-aligned) into bf16 hi/lo fragments
__device__ __forceinline__ void split8(const float* p, short8& hi, short8& lo) {
    float4_ a = *(const float4_*)p;
    float4_ b = *(const float4_*)(p + 4);
    float v[8] = {a[0], a[1], a[2], a[3], b[0], b[1], b[2], b[3]};
    #pragma unroll
    for (int j = 0; j < 8; ++j) {
        short h = bf16_hi(v[j]);
        hi[j] = h;
        lo[j] = bf16_hi(v[j] - bf16_f(h));
    }
}

// load B-fragment (8 k-rows of one 16-col slice) from global weights, hi/lo split
__device__ __forceinline__ void load_b(const float* __restrict__ W, int ldw,
                                       int colbase, int krow, short8& hi, short8& lo) {
    #pragma unroll
    for (int j = 0; j < 8; ++j) {
        float wv = W[(krow + j) * ldw + colbase];
        short h = bf16_hi(wv);
        hi[j] = h;
        lo[j] = bf16_hi(wv - bf16_f(h));
    }
}

// fp32-accurate product via 3 bf16 MFMAs (drop lo*lo)
__device__ __forceinline__ float4_ mm3(short8 ah, short8 al, short8 bh, short8 bl,
                                       float4_ acc) {
    acc = __builtin_amdgcn_mfma_f32_16x16x32_bf16(ah, bh, acc, 0, 0, 0);
    acc = __builtin_amdgcn_mfma_f32_16x16x32_bf16(al, bh, acc, 0, 0, 0);
    acc = __builtin_amdgcn_mfma_f32_16x16x32_bf16(ah, bl, acc, 0, 0, 0);
    return acc;
}

// ---------------- CSR build ----------------

__global__ void k_hist(const int* __restrict__ ei, int* __restrict__ cnt,
                       int* __restrict__ rank) {
    int e = blockIdx.x * blockDim.x + threadIdx.x;
    if (e < EE) rank[e] = atomicAdd(&cnt[ei[EE + e]], 1);
}

__global__ __launch_bounds__(1024) void k_scan1(const int* __restrict__ deg,
                                                int* __restrict__ excl,
                                                int* __restrict__ bsum) {
    __shared__ int ws[16];
    int tid = threadIdx.x, lane = tid & 63, w = tid >> 6;
    int gid = blockIdx.x * 1024 + tid;
    int v = (gid < NN) ? deg[gid] : 0;
    int x = v;
    #pragma unroll
    for (int d = 1; d < 64; d <<= 1) {
        int y = __shfl_up(x, d);
        if (lane >= d) x += y;
    }
    if (lane == 63) ws[w] = x;
    __syncthreads();
    if (tid == 0) {
        int acc = 0;
        for (int i = 0; i < 16; i++) { int t = ws[i]; ws[i] = acc; acc += t; }
        bsum[blockIdx.x] = acc;
    }
    __syncthreads();
    if (gid < NN) excl[gid] = x - v + ws[w];
}

__global__ void k_scan2(const int* __restrict__ bsum, int* __restrict__ boff, int nb) {
    if (threadIdx.x == 0) {
        int acc = 0;
        for (int i = 0; i < nb; i++) { boff[i] = acc; acc += bsum[i]; }
    }
}

__global__ __launch_bounds__(1024) void k_scan3(int* __restrict__ rp,
                                                const int* __restrict__ boff) {
    int gid = blockIdx.x * 1024 + threadIdx.x;
    if (gid < NN) rp[gid] += boff[blockIdx.x];
    if (gid == 0) rp[NN] = EE;
}

__global__ void k_scatter(const int* __restrict__ ei, const int* __restrict__ rp,
                          const int* __restrict__ rank, int* __restrict__ csrc) {
    int e = blockIdx.x * blockDim.x + threadIdx.x;
    if (e < EE) {
        int d = ei[EE + e];
        csrc[rp[d] + rank[e]] = ei[e];
    }
}

// ---------------- Encoder: h0 = x @ enc_W + enc_b, plus P0 = bf16(exp(msg)) ----------------

__global__ __launch_bounds__(256) void k_enc(const float* __restrict__ x,
                                             const float* __restrict__ W,
                                             const float* __restrict__ b,
                                             float* __restrict__ h,
                                             unsigned short* __restrict__ P0) {
    __shared__ float X[16 * 132];
    int tid = threadIdx.x, lane = tid & 63, w = tid >> 6;
    int nb = blockIdx.x * 16;
    int nq = lane >> 4, nr = lane & 15;
    int colbase = w * 16 + nr;

    {
        const float* src = x + (size_t)nb * IND + tid * 8;
        float4_ a = *(const float4_*)src;
        float4_ c = *(const float4_*)(src + 4);
        int m = tid >> 4, k8 = 8 * (tid & 15);
        *(float4_*)&X[m * 132 + k8] = a;
        *(float4_*)&X[m * 132 + k8 + 4] = c;
    }
    __syncthreads();

    float4_ acc = {};
    #pragma unroll
    for (int t = 0; t < 4; ++t) {
        short8 ah, al, bh, bl;
        split8(&X[nr * 132 + t * 32 + nq * 8], ah, al);
        load_b(W, HD, colbase, t * 32 + nq * 8, bh, bl);
        acc = mm3(ah, al, bh, bl, acc);
    }

    float bias = b[colbase];
    #pragma unroll
    for (int r = 0; r < 4; ++r) {
        int node = nb + nq * 4 + r;
        float y = acc[r] + bias;
        h[node * HD + colbase] = y;
        float msg = fminf(fmaxf(y, 0.f) + 1e-7f, 50.f);
        P0[node * HD + colbase] = f2b_rne(__expf(msg));
    }
}

// ---------------- GENConv layer: P-gather softmax agg + MFMA matmul + residual
//                  + fused next-layer prenorm -> Pout ----------------

__global__ __launch_bounds__(256) void k_layer(const unsigned short* __restrict__ Pin,
                                               const float* __restrict__ selfh,  // layer0 only
                                               const float* __restrict__ hres,
                                               float* __restrict__ hout,
                                               unsigned short* __restrict__ Pout,
                                               const int* __restrict__ rp,
                                               const int* __restrict__ csrc,
                                               const float* __restrict__ W,
                                               const float* __restrict__ b,
                                               const float* __restrict__ gnext,
                                               const float* __restrict__ bnext) {
    __shared__ float T[16 * 68];
    int tid = threadIdx.x, lane = tid & 63, w = tid >> 6;
    int nb = blockIdx.x * 16;
    int nq = lane >> 4, nr = lane & 15;
    int colbase = w * 16 + nr;

    // B fragments, register-resident (issued before the gather loop)
    short8 Bhi[2], Blo[2];
    #pragma unroll
    for (int t = 0; t < 2; ++t)
        load_b(W, HD, colbase, t * 32 + nq * 8, Bhi[t], Blo[t]);

    // gather: 4 nodes per wave; P = exp(msg) per src node, bf16.
    // n accumulates P*log2(P); agg = ln2 * n / s.
    #pragma unroll 1
    for (int i = 0; i < 4; ++i) {
        int node = nb + w * 4 + i;
        int beg = rp[node], end = rp[node + 1], deg = end - beg;
        float s = 0.f, n = 0.f;
        for (int chunk = 0; chunk < deg; chunk += 64) {
            int cnt = min(64, deg - chunk);
            int myidx = 0;
            if (chunk + lane < deg) myidx = csrc[beg + chunk + lane];
            int k = 0;
            for (; k + 16 <= cnt; k += 16) {
                unsigned short us[16];
                #pragma unroll
                for (int j = 0; j < 16; ++j) {
                    int src = __builtin_amdgcn_readlane(myidx, k + j);
                    us[j] = Pin[(src << 6) + lane];
                }
                #pragma unroll
                for (int j = 0; j < 16; ++j) {
                    float p = us2f(us[j]);
                    s += p;
                    n = fmaf(p, __log2f(p), n);
                }
            }
            for (; k + 4 <= cnt; k += 4) {
                unsigned short us[4];
                #pragma unroll
                for (int j = 0; j < 4; ++j) {
                    int src = __builtin_amdgcn_readlane(myidx, k + j);
                    us[j] = Pin[(src << 6) + lane];
                }
                #pragma unroll
                for (int j = 0; j < 4; ++j) {
                    float p = us2f(us[j]);
                    s += p;
                    n = fmaf(p, __log2f(p), n);
                }
            }
            for (; k < cnt; ++k) {
                int src = __builtin_amdgcn_readlane(myidx, k);
                float p = us2f(Pin[(src << 6) + lane]);
                s += p;
                n = fmaf(p, __log2f(p), n);
            }
        }
        float agg = LN2 * n / fmaxf(s, 1e-16f);  // 0 for isolated nodes
        float xv;
        if (selfh) {
            xv = selfh[node * HD + lane] + agg;  // layer 0: raw h0
        } else {
            float ps = us2f(Pin[(node << 6) + lane]);
            xv = LN2 * __log2f(ps) - 1e-7f + agg;  // y = msg - eps
        }
        T[(w * 4 + i) * 68 + lane] = xv;
    }
    __syncthreads();

    short8 Ahi[2], Alo[2];
    #pragma unroll
    for (int t = 0; t < 2; ++t)
        split8(&T[nr * 68 + t * 32 + nq * 8], Ahi[t], Alo[t]);
    __syncthreads();  // all A reads done before T is overwritten

    float4_ acc = {};
    #pragma unroll
    for (int t = 0; t < 2; ++t)
        acc = mm3(Ahi[t], Alo[t], Bhi[t], Blo[t], acc);

    float bias = b[colbase];
    #pragma unroll
    for (int r = 0; r < 4; ++r) {
        int m = nq * 4 + r;
        int node = nb + m;
        float v = acc[r] + bias;
        if (hres) v += hres[node * HD + colbase];
        hout[node * HD + colbase] = v;
        T[m * 68 + colbase] = v;
    }
    if (!Pout) return;
    __syncthreads();

    // LN phase: thread -> node tid>>4, 4 channels; emit P = bf16(exp(msg))
    int m = tid >> 4, c4 = (tid & 15) * 4;
    float4_ vv = *(const float4_*)&T[m * 68 + c4];
    float ps_ = (vv[0] + vv[1]) + (vv[2] + vv[3]);
    float pq_ = (vv[0] * vv[0] + vv[1] * vv[1]) + (vv[2] * vv[2] + vv[3] * vv[3]);
    #pragma unroll
    for (int d = 8; d; d >>= 1) {
        ps_ += __shfl_xor(ps_, d);
        pq_ += __shfl_xor(pq_, d);
    }
    float mu = ps_ * (1.f / 64.f);
    float var = pq_ * (1.f / 64.f) - mu * mu;
    float inv = rsqrtf(fmaxf(var, 0.f) + 1e-5f);
    float4_ g4 = *(const float4_*)&gnext[c4];
    float4_ b4 = *(const float4_*)&bnext[c4];
    ushort4_ po;
    #pragma unroll
    for (int j = 0; j < 4; ++j) {
        float y = fmaxf((vv[j] - mu) * inv * g4[j] + b4[j], 0.f);
        float msg = fminf(y + 1e-7f, 50.f);
        po[j] = f2b_rne(__expf(msg));
    }
    *(ushort4_*)&Pout[(nb + m) * HD + c4] = po;
}

// ---------------- Predictor: out = h @ pred_W + pred_b  (MFMA) ----------------

__global__ __launch_bounds__(256) void k_pred(const float* __restrict__ h,
                                              const float* __restrict__ W,
                                              const float* __restrict__ b,
                                              float* __restrict__ out) {
    __shared__ float T[16 * 68];
    int tid = threadIdx.x, lane = tid & 63, w = tid >> 6;
    int nb = blockIdx.x * 16;
    int nq = lane >> 4, nr = lane & 15;

    {
        const float* src = h + (size_t)nb * HD + tid * 4;
        float4_ a = *(const float4_*)src;
        int m = tid >> 4, k4 = 4 * (tid & 15);
        *(float4_*)&T[m * 68 + k4] = a;
    }
    __syncthreads();

    short8 Ahi[2], Alo[2];
    #pragma unroll
    for (int t = 0; t < 2; ++t)
        split8(&T[nr * 68 + t * 32 + nq * 8], Ahi[t], Alo[t]);

    for (int tt = w; tt < 7; tt += 4) {
        int colbase = tt * 16 + nr;
        float4_ acc = {};
        #pragma unroll
        for (int t = 0; t < 2; ++t) {
            short8 bh, bl;
            load_b(W, OUTD, colbase, t * 32 + nq * 8, bh, bl);
            acc = mm3(Ahi[t], Alo[t], bh, bl, acc);
        }
        float bias = b[colbase];
        #pragma unroll
        for (int r = 0; r < 4; ++r) {
            int node = nb + nq * 4 + r;
            out[node * OUTD + colbase] = acc[r] + bias;
        }
    }
}

// ---------------- Launch ----------------

extern "C" void kernel_launch(void* const* d_in, const int* in_sizes, int n_in,
                              void* d_out, int out_size, void* d_ws, size_t ws_size,
                              hipStream_t stream) {
    const float* x    = (const float*)d_in[0];
    const int*   ei   = (const int*)d_in[1];
    const float* encW = (const float*)d_in[2];
    const float* encb = (const float*)d_in[3];
    const float* lng  = (const float*)d_in[4];
    const float* lnb  = (const float*)d_in[5];
    const float* mlpW = (const float*)d_in[6];
    const float* mlpb = (const float*)d_in[7];
    const float* pW   = (const float*)d_in[8];
    const float* pb   = (const float*)d_in[9];
    float* out = (float*)d_out;

    float* hA  = (float*)d_ws;
    float* hB  = hA + (size_t)NN * HD;
    unsigned short* PA = (unsigned short*)(hB + (size_t)NN * HD);
    unsigned short* PB = PA + (size_t)NN * HD;
    int* rp   = (int*)(PB + (size_t)NN * HD);
    int* cnt  = rp + (NN + 1);
    int* csrc = cnt + NN;
    int* rank = csrc + EE;
    int* bsum = rank + EE;
    int* boff = bsum + 64;

    // CSR build (per call; ws is re-poisoned each launch)
    hipMemsetAsync(cnt, 0, NN * sizeof(int), stream);
    k_hist<<<(EE + 255) / 256, 256, 0, stream>>>(ei, cnt, rank);
    const int NB = (NN + 1023) / 1024;  // 49
    k_scan1<<<NB, 1024, 0, stream>>>(cnt, rp, bsum);
    k_scan2<<<1, 64, 0, stream>>>(bsum, boff, NB);
    k_scan3<<<NB, 1024, 0, stream>>>(rp, boff);
    k_scatter<<<(EE + 255) / 256, 256, 0, stream>>>(ei, rp, rank, csrc);

    // Encoder -> h_0 in hA, P_0 in PA
    k_enc<<<NN / 16, 256, 0, stream>>>(x, encW, encb, hA, PA);

    // Layer 0: self term = raw h0; writes h_1 -> hB, P_1 -> PB
    k_layer<<<NN / 16, 256, 0, stream>>>(PA, hA, nullptr, hB, PB, rp, csrc,
                                         mlpW, mlpb, lng, lnb);

    float* hres = hB;   // h_1
    float* hdst = hA;
    unsigned short* pc = PB;
    unsigned short* pn = PA;
    for (int l = 1; l < LL; ++l) {
        bool last = (l == LL - 1);
        k_layer<<<NN / 16, 256, 0, stream>>>(pc, nullptr, hres, hdst,
                                             last ? nullptr : pn,
                                             rp, csrc,
                                             mlpW + (size_t)l * HD * HD,
                                             mlpb + (size_t)l * HD,
                                             last ? nullptr : lng + (size_t)l * HD,
                                             last ? nullptr : lnb + (size_t)l * HD);
        float* t = hres; hres = hdst; hdst = t;
        unsigned short* u = pc; pc = pn; pn = u;
    }

    // Predictor on h_14
    k_pred<<<NN / 16, 256, 0, stream>>>(hres, pW, pb, out);
}

// Round 8
// 736.177 us; speedup vs baseline: 2.7682x; 1.0288x over previous
//
#include <hip/hip_runtime.h>
#include <hip/hip_bf16.h>

#define NN 50000
#define EE 800000
#define HD 64
#define LL 14
#define IND 128
#define OUTD 112
#define LN2 0.69314718056f

typedef __attribute__((ext_vector_type(8))) short short8;
typedef __attribute__((ext_vector_type(4))) float float4_;
typedef __attribute__((ext_vector_type(4))) unsigned short ushort4_;

__device__ __forceinline__ short bf16_hi(float x) {
    return (short)(__float_as_uint(x) >> 16);  // truncation split
}
__device__ __forceinline__ float bf16_f(short s) {
    return __uint_as_float(((unsigned)(unsigned short)s) << 16);
}
__device__ __forceinline__ float us2f(unsigned short u) {
    return __uint_as_float(((unsigned)u) << 16);
}
// round-to-nearest-even fp32 -> bf16 bits
__device__ __forceinline__ unsigned short f2b_rne(float x) {
    unsigned u = __float_as_uint(x);
    u += 0x7fffu + ((u >> 16) & 1u);
    return (unsigned short)(u >> 16);
}

// split 8 consecutive fp32 (16B-aligned) into bf16 hi/lo fragments
__device__ __forceinline__ void split8(const float* p, short8& hi, short8& lo) {
    float4_ a = *(const float4_*)p;
    float4_ b = *(const float4_*)(p + 4);
    float v[8] = {a[0], a[1], a[2], a[3], b[0], b[1], b[2], b[3]};
    #pragma unroll
    for (int j = 0; j < 8; ++j) {
        short h = bf16_hi(v[j]);
        hi[j] = h;
        lo[j] = bf16_hi(v[j] - bf16_f(h));
    }
}

// load B-fragment (8 k-rows of one 16-col slice) from global weights, hi/lo split
__device__ __forceinline__ void load_b(const float* __restrict__ W, int ldw,
                                       int colbase, int krow, short8& hi, short8& lo) {
    #pragma unroll
    for (int j = 0; j < 8; ++j) {
        float wv = W[(krow + j) * ldw + colbase];
        short h = bf16_hi(wv);
        hi[j] = h;
        lo[j] = bf16_hi(wv - bf16_f(h));
    }
}

// fp32-accurate product via 3 bf16 MFMAs (drop lo*lo)
__device__ __forceinline__ float4_ mm3(short8 ah, short8 al, short8 bh, short8 bl,
                                       float4_ acc) {
    acc = __builtin_amdgcn_mfma_f32_16x16x32_bf16(ah, bh, acc, 0, 0, 0);
    acc = __builtin_amdgcn_mfma_f32_16x16x32_bf16(al, bh, acc, 0, 0, 0);
    acc = __builtin_amdgcn_mfma_f32_16x16x32_bf16(ah, bl, acc, 0, 0, 0);
    return acc;
}

// ---------------- CSR build ----------------

__global__ void k_hist(const int* __restrict__ ei, int* __restrict__ cnt,
                       int* __restrict__ rank) {
    int e = blockIdx.x * blockDim.x + threadIdx.x;
    if (e < EE) rank[e] = atomicAdd(&cnt[ei[EE + e]], 1);
}

__global__ __launch_bounds__(1024) void k_scan1(const int* __restrict__ deg,
                                                int* __restrict__ excl,
                                                int* __restrict__ bsum) {
    __shared__ int ws[16];
    int tid = threadIdx.x, lane = tid & 63, w = tid >> 6;
    int gid = blockIdx.x * 1024 + tid;
    int v = (gid < NN) ? deg[gid] : 0;
    int x = v;
    #pragma unroll
    for (int d = 1; d < 64; d <<= 1) {
        int y = __shfl_up(x, d);
        if (lane >= d) x += y;
    }
    if (lane == 63) ws[w] = x;
    __syncthreads();
    if (tid == 0) {
        int acc = 0;
        for (int i = 0; i < 16; i++) { int t = ws[i]; ws[i] = acc; acc += t; }
        bsum[blockIdx.x] = acc;
    }
    __syncthreads();
    if (gid < NN) excl[gid] = x - v + ws[w];
}

__global__ void k_scan2(const int* __restrict__ bsum, int* __restrict__ boff, int nb) {
    if (threadIdx.x == 0) {
        int acc = 0;
        for (int i = 0; i < nb; i++) { boff[i] = acc; acc += bsum[i]; }
    }
}

__global__ __launch_bounds__(1024) void k_scan3(int* __restrict__ rp,
                                                const int* __restrict__ boff) {
    int gid = blockIdx.x * 1024 + threadIdx.x;
    if (gid < NN) rp[gid] += boff[blockIdx.x];
    if (gid == 0) rp[NN] = EE;
}

__global__ void k_scatter(const int* __restrict__ ei, const int* __restrict__ rp,
                          const int* __restrict__ rank, int* __restrict__ csrc) {
    int e = blockIdx.x * blockDim.x + threadIdx.x;
    if (e < EE) {
        int d = ei[EE + e];
        csrc[rp[d] + rank[e]] = ei[e];
    }
}

// ---------------- Encoder: h0 = x @ enc_W + enc_b, plus P0 = bf16(exp(msg)) ----------------

__global__ __launch_bounds__(256) void k_enc(const float* __restrict__ x,
                                             const float* __restrict__ W,
                                             const float* __restrict__ b,
                                             float* __restrict__ h,
                                             unsigned short* __restrict__ P0) {
    __shared__ float X[16 * 132];
    int tid = threadIdx.x, lane = tid & 63, w = tid >> 6;
    int nb = blockIdx.x * 16;
    int nq = lane >> 4, nr = lane & 15;
    int colbase = w * 16 + nr;

    {
        const float* src = x + (size_t)nb * IND + tid * 8;
        float4_ a = *(const float4_*)src;
        float4_ c = *(const float4_*)(src + 4);
        int m = tid >> 4, k8 = 8 * (tid & 15);
        *(float4_*)&X[m * 132 + k8] = a;
        *(float4_*)&X[m * 132 + k8 + 4] = c;
    }
    __syncthreads();

    float4_ acc = {};
    #pragma unroll
    for (int t = 0; t < 4; ++t) {
        short8 ah, al, bh, bl;
        split8(&X[nr * 132 + t * 32 + nq * 8], ah, al);
        load_b(W, HD, colbase, t * 32 + nq * 8, bh, bl);
        acc = mm3(ah, al, bh, bl, acc);
    }

    float bias = b[colbase];
    #pragma unroll
    for (int r = 0; r < 4; ++r) {
        int node = nb + nq * 4 + r;
        float y = acc[r] + bias;
        h[node * HD + colbase] = y;
        float msg = fminf(fmaxf(y, 0.f) + 1e-7f, 50.f);
        P0[node * HD + colbase] = f2b_rne(__expf(msg));
    }
}

// ---------------- GENConv layer: quarter-wave P-gather softmax agg + MFMA matmul
//                  + residual + fused next-layer prenorm -> Pout ----------------

__global__ __launch_bounds__(256) void k_layer(const unsigned short* __restrict__ Pin,
                                               const float* __restrict__ selfh,  // layer0 only
                                               const float* __restrict__ hres,
                                               float* __restrict__ hout,
                                               unsigned short* __restrict__ Pout,
                                               const int* __restrict__ rp,
                                               const int* __restrict__ csrc,
                                               const float* __restrict__ W,
                                               const float* __restrict__ b,
                                               const float* __restrict__ gnext,
                                               const float* __restrict__ bnext) {
    __shared__ float T[16 * 68];
    int tid = threadIdx.x, lane = tid & 63, w = tid >> 6;
    int nb = blockIdx.x * 16;
    int nq = lane >> 4, nr = lane & 15;
    int colbase = w * 16 + nr;

    // B fragments, register-resident (issued before the gather loop)
    short8 Bhi[2], Blo[2];
    #pragma unroll
    for (int t = 0; t < 2; ++t)
        load_b(W, HD, colbase, t * 32 + nq * 8, Bhi[t], Blo[t]);

    // quarter-wave gather: group g (lane>>4) owns one edge per batch;
    // lane covers channels ci*4 .. ci*4+3 (dwordx2 of bf16 P values).
    // One wave-load = 4 edges. s,n per channel; agg = ln2 * n / s.
    int g = lane >> 4;
    int ci = lane & 15;
    #pragma unroll 1
    for (int i = 0; i < 4; ++i) {
        int node = nb + w * 4 + i;
        int beg = rp[node], end = rp[node + 1], deg = end - beg;
        float s0 = 0.f, s1 = 0.f, s2 = 0.f, s3 = 0.f;
        float n0 = 0.f, n1 = 0.f, n2 = 0.f, n3 = 0.f;
        for (int chunk = 0; chunk < deg; chunk += 64) {
            int cnt = min(64, deg - chunk);
            int myidx = 0;
            if (chunk + lane < deg) myidx = csrc[beg + chunk + lane];
            int nb4 = (cnt + 3) >> 2;
            #pragma unroll 2
            for (int k = 0; k < nb4; ++k) {
                int src = __shfl(myidx, k * 4 + g);   // ds_bpermute
                const unsigned* pp = (const unsigned*)(Pin + ((size_t)src << 6)) + ci * 2;
                unsigned d0 = pp[0], d1 = pp[1];
                if (k * 4 + g >= cnt) { d0 = 0u; d1 = 0u; }
                float p0 = __uint_as_float(d0 << 16);
                float p1 = __uint_as_float(d0 & 0xffff0000u);
                float p2 = __uint_as_float(d1 << 16);
                float p3 = __uint_as_float(d1 & 0xffff0000u);
                s0 += p0; s1 += p1; s2 += p2; s3 += p3;
                n0 = fmaf(p0, __log2f(fmaxf(p0, 1e-20f)), n0);
                n1 = fmaf(p1, __log2f(fmaxf(p1, 1e-20f)), n1);
                n2 = fmaf(p2, __log2f(fmaxf(p2, 1e-20f)), n2);
                n3 = fmaf(p3, __log2f(fmaxf(p3, 1e-20f)), n3);
            }
        }
        // reduce across the 4 quarter-wave groups (lanes differing in bits 4,5)
        #pragma unroll
        for (int d = 16; d < 64; d <<= 1) {
            s0 += __shfl_xor(s0, d); s1 += __shfl_xor(s1, d);
            s2 += __shfl_xor(s2, d); s3 += __shfl_xor(s3, d);
            n0 += __shfl_xor(n0, d); n1 += __shfl_xor(n1, d);
            n2 += __shfl_xor(n2, d); n3 += __shfl_xor(n3, d);
        }
        if (g == 0) {
            float a0 = LN2 * n0 / fmaxf(s0, 1e-16f);
            float a1 = LN2 * n1 / fmaxf(s1, 1e-16f);
            float a2 = LN2 * n2 / fmaxf(s2, 1e-16f);
            float a3 = LN2 * n3 / fmaxf(s3, 1e-16f);
            float4_ xv;
            if (selfh) {
                float4_ sf = *(const float4_*)&selfh[(size_t)node * HD + ci * 4];
                xv[0] = sf[0] + a0; xv[1] = sf[1] + a1;
                xv[2] = sf[2] + a2; xv[3] = sf[3] + a3;
            } else {
                const unsigned* pp = (const unsigned*)(Pin + ((size_t)node << 6)) + ci * 2;
                unsigned d0 = pp[0], d1 = pp[1];
                xv[0] = LN2 * __log2f(__uint_as_float(d0 << 16)) - 1e-7f + a0;
                xv[1] = LN2 * __log2f(__uint_as_float(d0 & 0xffff0000u)) - 1e-7f + a1;
                xv[2] = LN2 * __log2f(__uint_as_float(d1 << 16)) - 1e-7f + a2;
                xv[3] = LN2 * __log2f(__uint_as_float(d1 & 0xffff0000u)) - 1e-7f + a3;
            }
            *(float4_*)&T[(w * 4 + i) * 68 + ci * 4] = xv;
        }
    }
    __syncthreads();

    short8 Ahi[2], Alo[2];
    #pragma unroll
    for (int t = 0; t < 2; ++t)
        split8(&T[nr * 68 + t * 32 + nq * 8], Ahi[t], Alo[t]);
    __syncthreads();  // all A reads done before T is overwritten

    float4_ acc = {};
    #pragma unroll
    for (int t = 0; t < 2; ++t)
        acc = mm3(Ahi[t], Alo[t], Bhi[t], Blo[t], acc);

    float bias = b[colbase];
    #pragma unroll
    for (int r = 0; r < 4; ++r) {
        int m = nq * 4 + r;
        int node = nb + m;
        float v = acc[r] + bias;
        if (hres) v += hres[node * HD + colbase];
        hout[node * HD + colbase] = v;
        T[m * 68 + colbase] = v;
    }
    if (!Pout) return;
    __syncthreads();

    // LN phase: thread -> node tid>>4, 4 channels; emit P = bf16(exp(msg))
    int m = tid >> 4, c4 = (tid & 15) * 4;
    float4_ vv = *(const float4_*)&T[m * 68 + c4];
    float ps_ = (vv[0] + vv[1]) + (vv[2] + vv[3]);
    float pq_ = (vv[0] * vv[0] + vv[1] * vv[1]) + (vv[2] * vv[2] + vv[3] * vv[3]);
    #pragma unroll
    for (int d = 8; d; d >>= 1) {
        ps_ += __shfl_xor(ps_, d);
        pq_ += __shfl_xor(pq_, d);
    }
    float mu = ps_ * (1.f / 64.f);
    float var = pq_ * (1.f / 64.f) - mu * mu;
    float inv = rsqrtf(fmaxf(var, 0.f) + 1e-5f);
    float4_ g4 = *(const float4_*)&gnext[c4];
    float4_ b4 = *(const float4_*)&bnext[c4];
    ushort4_ po;
    #pragma unroll
    for (int j = 0; j < 4; ++j) {
        float y = fmaxf((vv[j] - mu) * inv * g4[j] + b4[j], 0.f);
        float msg = fminf(y + 1e-7f, 50.f);
        po[j] = f2b_rne(__expf(msg));
    }
    *(ushort4_*)&Pout[(nb + m) * HD + c4] = po;
}

// ---------------- Predictor: out = h @ pred_W + pred_b  (MFMA) ----------------

__global__ __launch_bounds__(256) void k_pred(const float* __restrict__ h,
                                              const float* __restrict__ W,
                                              const float* __restrict__ b,
                                              float* __restrict__ out) {
    __shared__ float T[16 * 68];
    int tid = threadIdx.x, lane = tid & 63, w = tid >> 6;
    int nb = blockIdx.x * 16;
    int nq = lane >> 4, nr = lane & 15;

    {
        const float* src = h + (size_t)nb * HD + tid * 4;
        float4_ a = *(const float4_*)src;
        int m = tid >> 4, k4 = 4 * (tid & 15);
        *(float4_*)&T[m * 68 + k4] = a;
    }
    __syncthreads();

    short8 Ahi[2], Alo[2];
    #pragma unroll
    for (int t = 0; t < 2; ++t)
        split8(&T[nr * 68 + t * 32 + nq * 8], Ahi[t], Alo[t]);

    for (int tt = w; tt < 7; tt += 4) {
        int colbase = tt * 16 + nr;
        float4_ acc = {};
        #pragma unroll
        for (int t = 0; t < 2; ++t) {
            short8 bh, bl;
            load_b(W, OUTD, colbase, t * 32 + nq * 8, bh, bl);
            acc = mm3(Ahi[t], Alo[t], bh, bl, acc);
        }
        float bias = b[colbase];
        #pragma unroll
        for (int r = 0; r < 4; ++r) {
            int node = nb + nq * 4 + r;
            out[node * OUTD + colbase] = acc[r] + bias;
        }
    }
}

// ---------------- Launch ----------------

extern "C" void kernel_launch(void* const* d_in, const int* in_sizes, int n_in,
                              void* d_out, int out_size, void* d_ws, size_t ws_size,
                              hipStream_t stream) {
    const float* x    = (const float*)d_in[0];
    const int*   ei   = (const int*)d_in[1];
    const float* encW = (const float*)d_in[2];
    const float* encb = (const float*)d_in[3];
    const float* lng  = (const float*)d_in[4];
    const float* lnb  = (const float*)d_in[5];
    const float* mlpW = (const float*)d_in[6];
    const float* mlpb = (const float*)d_in[7];
    const float* pW   = (const float*)d_in[8];
    const float* pb   = (const float*)d_in[9];
    float* out = (float*)d_out;

    float* hA  = (float*)d_ws;
    float* hB  = hA + (size_t)NN * HD;
    unsigned short* PA = (unsigned short*)(hB + (size_t)NN * HD);
    unsigned short* PB = PA + (size_t)NN * HD;
    int* rp   = (int*)(PB + (size_t)NN * HD);
    int* cnt  = rp + (NN + 1);
    int* csrc = cnt + NN;
    int* rank = csrc + EE;
    int* bsum = rank + EE;
    int* boff = bsum + 64;

    // CSR build (per call; ws is re-poisoned each launch)
    hipMemsetAsync(cnt, 0, NN * sizeof(int), stream);
    k_hist<<<(EE + 255) / 256, 256, 0, stream>>>(ei, cnt, rank);
    const int NB = (NN + 1023) / 1024;  // 49
    k_scan1<<<NB, 1024, 0, stream>>>(cnt, rp, bsum);
    k_scan2<<<1, 64, 0, stream>>>(bsum, boff, NB);
    k_scan3<<<NB, 1024, 0, stream>>>(rp, boff);
    k_scatter<<<(EE + 255) / 256, 256, 0, stream>>>(ei, rp, rank, csrc);

    // Encoder -> h_0 in hA, P_0 in PA
    k_enc<<<NN / 16, 256, 0, stream>>>(x, encW, encb, hA, PA);

    // Layer 0: self term = raw h0; writes h_1 -> hB, P_1 -> PB
    k_layer<<<NN / 16, 256, 0, stream>>>(PA, hA, nullptr, hB, PB, rp, csrc,
                                         mlpW, mlpb, lng, lnb);

    float* hres = hB;   // h_1
    float* hdst = hA;
    unsigned short* pc = PB;
    unsigned short* pn = PA;
    for (int l = 1; l < LL; ++l) {
        bool last = (l == LL - 1);
        k_layer<<<NN / 16, 256, 0, stream>>>(pc, nullptr, hres, hdst,
                                             last ? nullptr : pn,
                                             rp, csrc,
                                             mlpW + (size_t)l * HD * HD,
                                             mlpb + (size_t)l * HD,
                                             last ? nullptr : lng + (size_t)l * HD,
                                             last ? nullptr : lnb + (size_t)l * HD);
        float* t = hres; hres = hdst; hdst = t;
        unsigned short* u = pc; pc = pn; pn = u;
    }

    // Predictor on h_14
    k_pred<<<NN / 16, 256, 0, stream>>>(hres, pW, pb, out);
}